// Round 1
// baseline (254.645 us; speedup 1.0000x reference)
//
#include <hip/hip_runtime.h>
#include <math.h>

// 31x31 depthwise Gaussian (sigma=3) == separable 25-tap 1D Gaussian applied
// twice (taps beyond radius 12 are exactly zero in the reference kernel).
// Reflection pad 15 in the reference, but only +/-12 is ever touched by
// nonzero weights -> reflect indices at radius 12.

#define IW 512
#define IH 512
#define NPLANES 96          // 32 batch * 3 channels, contiguous NCHW planes
#define RAD 12
#define TAPS 25
#define TW 64               // output tile width
#define TH 64               // output tile height
#define MH (TH + 2*RAD)     // 88 intermediate rows (with vertical halo)
#define MWP 65              // padded LDS stride (odd -> conflict-free columns)

__global__ __launch_bounds__(256)
void gauss_blur_sep_kernel(const float* __restrict__ x,
                           const float* __restrict__ wgt,
                           float* __restrict__ out)
{
    __shared__ float mid[MH * MWP];   // 88*65*4 = 22880 B
    __shared__ float k1s[TAPS];

    const int tid = threadIdx.x;
    const int z   = blockIdx.z;                 // plane index 0..95
    const int ch  = z - (z / 3) * 3;            // channel 0..2 (weights identical, but be exact)

    // Extract the 1D kernel from the 2D weight: w2d = outer(f, f),
    // f[15] = sqrt(w2d[15][15]); k1[t] = w2d[15][3+t] / f[15]  (t=0..24 <-> dx=-12..12)
    if (tid < TAPS) {
        const float* wp = wgt + ch * 31 * 31;
        float wc = wp[15 * 31 + 15];
        k1s[tid] = wp[15 * 31 + 3 + tid] / sqrtf(wc);
    }
    __syncthreads();

    float kk[TAPS];
#pragma unroll
    for (int t = 0; t < TAPS; ++t) kk[t] = k1s[t];

    const int r0g = blockIdx.y * TH;            // global output row base of tile
    const int c0g = blockIdx.x * TW;            // global output col base of tile
    const float* __restrict__ src = x + (size_t)z * (IW * IH);

    // ---------- horizontal pass: global -> mid (LDS) ----------
    // tasks: 88 rows x 8 column-groups of 8 outputs; each task loads a
    // 32-float window (8 aligned float4 loads when interior) and produces
    // 8 horizontally-blurred values.
    for (int task = tid; task < MH * (TW / 8); task += 256) {
        const int g = task & 7;        // column group
        const int m = task >> 3;       // intermediate row 0..87
        int gr = r0g + m - RAD;
        gr = gr < 0 ? -gr : (gr >= IH ? 2 * IH - 2 - gr : gr);   // reflect rows
        const float* __restrict__ srow = src + (size_t)gr * IW;
        const int wc0 = c0g + g * 8 - RAD;       // window start col (mult of 4)

        float v[32];
        if (wc0 >= 0 && wc0 + 32 <= IW) {
            const float4* __restrict__ p = (const float4*)(srow + wc0);
#pragma unroll
            for (int q = 0; q < 8; ++q) {
                float4 f = p[q];
                v[4*q+0] = f.x; v[4*q+1] = f.y; v[4*q+2] = f.z; v[4*q+3] = f.w;
            }
        } else {
#pragma unroll
            for (int j = 0; j < 32; ++j) {
                int gc = wc0 + j;
                gc = gc < 0 ? -gc : (gc >= IW ? 2 * IW - 2 - gc : gc); // reflect cols
                v[j] = srow[gc];
            }
        }
#pragma unroll
        for (int o = 0; o < 8; ++o) {
            float acc = 0.f;
#pragma unroll
            for (int t = 0; t < TAPS; ++t) acc = fmaf(v[o + t], kk[t], acc);
            mid[m * MWP + g * 8 + o] = acc;
        }
    }
    __syncthreads();

    // ---------- vertical pass: mid (LDS) -> out, register sliding window ----------
    // wave lanes span 64 contiguous columns -> conflict-free LDS reads,
    // coalesced global stores. Each thread: 1 column x 16 rows, 40 LDS reads
    // feed 400 FMAs (2.5 reads/output).
    const int c  = tid & 63;
    const int rb = (tid >> 6) * 16;   // local output row base for this thread

    float acc[16];
#pragma unroll
    for (int o = 0; o < 16; ++o) acc[o] = 0.f;

#pragma unroll
    for (int m2 = 0; m2 < 40; ++m2) {
        float vv = mid[(rb + m2) * MWP + c];
#pragma unroll
        for (int o = 0; o < 16; ++o) {
            const int t = m2 - o;
            if (t >= 0 && t < TAPS) acc[o] = fmaf(vv, kk[t], acc[o]);
        }
    }

    float* __restrict__ dst = out + (size_t)z * (IW * IH) + (size_t)r0g * IW + c0g + c;
#pragma unroll
    for (int o = 0; o < 16; ++o) {
        dst[(size_t)(rb + o) * IW] = acc[o];
    }
}

extern "C" void kernel_launch(void* const* d_in, const int* in_sizes, int n_in,
                              void* d_out, int out_size, void* d_ws, size_t ws_size,
                              hipStream_t stream)
{
    const float* x   = (const float*)d_in[0];
    const float* wgt = (const float*)d_in[1];
    float* out = (float*)d_out;

    dim3 grid(IW / TW, IH / TH, NPLANES);   // 8 x 8 x 96 = 6144 blocks
    gauss_blur_sep_kernel<<<grid, dim3(256), 0, stream>>>(x, wgt, out);
}